// Round 7
// baseline (145.478 us; speedup 1.0000x reference)
//
#include <hip/hip_runtime.h>
#include <hip/hip_bf16.h>

constexpr int BB = 4;
constexpr int TT = 1024;
constexpr int DD = 512;
constexpr int PP = 64;
constexpr int MM = 256;

constexpr float CSCALE = 2.8853900817779268f; // 2*log2(e)
constexpr float L2E = 1.4426950408889634f;    // log2(e)

typedef __attribute__((ext_vector_type(8))) short v8s;
typedef __attribute__((ext_vector_type(4))) float v4f;
typedef __attribute__((ext_vector_type(2))) float v2f;
typedef unsigned int __attribute__((address_space(1))) gu32;
typedef unsigned int __attribute__((address_space(3))) su32;

__device__ __forceinline__ unsigned short f2bf(float f) {
    unsigned u = __builtin_bit_cast(unsigned, f);
    unsigned r = (u + 0x7fffu + ((u >> 16) & 1u)) >> 16;
    return (unsigned short)r;
}
__device__ __forceinline__ float bf2f(unsigned short h) {
    return __builtin_bit_cast(float, (unsigned)h << 16);
}
__device__ __forceinline__ void split2(float v, unsigned short& h, unsigned short& l) {
    unsigned short hh = f2bf(v);
    h = hh;
    l = f2bf(v - bf2f(hh));
}
__device__ __forceinline__ void gld_lds16(const void* g, void* l) {
    __builtin_amdgcn_global_load_lds((const gu32*)g, (su32*)l, 16, 0, 0);
}
__device__ __forceinline__ v2f pfma(v2f a, v2f b, v2f c) {
    return __builtin_elementwise_fma(a, b, c);   // -> v_pk_fma_f32 on gfx950
}

// prep1: blocks [0,512): x tiles -> xt (bf16 transpose);
//        [512,528): W1|W2 -> WhT/WlT (bf16 hi/lo, [n][k] transposed);
//        528: ec_proj -> E3.
__global__ __launch_bounds__(256) void prep1_kernel(
    const float* __restrict__ x, const float* __restrict__ ec,
    const float* __restrict__ W1, const float* __restrict__ W2,
    const float* __restrict__ W3, const float* __restrict__ b3,
    unsigned short* __restrict__ xt,
    unsigned short* __restrict__ WhT, unsigned short* __restrict__ WlT,
    float* __restrict__ E3) {
    __shared__ float tile[64][65];
    int bid = blockIdx.x;
    int tid = threadIdx.x;
    if (bid < 512) {
        int d0 = (bid & 7) << 6;
        int u0 = ((bid >> 3) & 15) << 6;
        int b = bid >> 7;
        int c4 = (tid & 15) << 2, r = tid >> 4;
        #pragma unroll
        for (int i = 0; i < 4; i++) {
            int row = r + (i << 4);
            float4 v = *(const float4*)(x + ((size_t)b * TT + u0 + row) * DD + d0 + c4);
            tile[row][c4 + 0] = v.x;
            tile[row][c4 + 1] = v.y;
            tile[row][c4 + 2] = v.z;
            tile[row][c4 + 3] = v.w;
        }
        __syncthreads();
        int dd = tid >> 2;
        int uq = (tid & 3) << 4;
        unsigned short us[16];
        #pragma unroll
        for (int j = 0; j < 16; j++) us[j] = f2bf(tile[uq + j][dd]);
        uint4 w0, w1;
        w0.x = us[0] | ((unsigned)us[1] << 16);  w0.y = us[2] | ((unsigned)us[3] << 16);
        w0.z = us[4] | ((unsigned)us[5] << 16);  w0.w = us[6] | ((unsigned)us[7] << 16);
        w1.x = us[8] | ((unsigned)us[9] << 16);  w1.y = us[10] | ((unsigned)us[11] << 16);
        w1.z = us[12] | ((unsigned)us[13] << 16); w1.w = us[14] | ((unsigned)us[15] << 16);
        unsigned short* dst = xt + ((size_t)b * DD + d0 + dd) * TT + u0 + uq;
        *(uint4*)dst = w0;
        *(uint4*)(dst + 8) = w1;
    } else if (bid < 528) {
        // W transpose: block w covers k-slice [w*32, w*32+32), all 128 n.
        int w = bid - 512;
        int n = tid >> 1;               // 0..127
        int kb = (w << 5) + ((tid & 1) << 4);
        unsigned short hs[16], ls[16];
        #pragma unroll
        for (int kk = 0; kk < 16; kk++) {
            int k = kb + kk;
            float v = (n < 64) ? W1[k * PP + n] : W2[k * PP + (n - 64)];
            split2(v, hs[kk], ls[kk]);
        }
        uint4 a, bqq;
        a.x = hs[0] | ((unsigned)hs[1] << 16);   a.y = hs[2] | ((unsigned)hs[3] << 16);
        a.z = hs[4] | ((unsigned)hs[5] << 16);   a.w = hs[6] | ((unsigned)hs[7] << 16);
        bqq.x = hs[8] | ((unsigned)hs[9] << 16); bqq.y = hs[10] | ((unsigned)hs[11] << 16);
        bqq.z = hs[12] | ((unsigned)hs[13] << 16); bqq.w = hs[14] | ((unsigned)hs[15] << 16);
        *(uint4*)(WhT + (size_t)n * DD + kb) = a;
        *(uint4*)(WhT + (size_t)n * DD + kb + 8) = bqq;
        a.x = ls[0] | ((unsigned)ls[1] << 16);   a.y = ls[2] | ((unsigned)ls[3] << 16);
        a.z = ls[4] | ((unsigned)ls[5] << 16);   a.w = ls[6] | ((unsigned)ls[7] << 16);
        bqq.x = ls[8] | ((unsigned)ls[9] << 16); bqq.y = ls[10] | ((unsigned)ls[11] << 16);
        bqq.z = ls[12] | ((unsigned)ls[13] << 16); bqq.w = ls[14] | ((unsigned)ls[15] << 16);
        *(uint4*)(WlT + (size_t)n * DD + kb) = a;
        *(uint4*)(WlT + (size_t)n * DD + kb + 8) = bqq;
    } else {
        int b = tid >> 6, p = tid & 63;
        float a = b3[p];
        const float* e = ec + (size_t)b * MM;
        #pragma unroll 4
        for (int m = 0; m < MM; m++) a = fmaf(e[m], W3[m * PP + p], a);
        E3[b * PP + p] = __builtin_amdgcn_exp2f(a * CSCALE);
    }
}

// prep2: proj GEMM h = x (4096x512) @ [W1|W2] (512x128) via 3-term bf16-split MFMA.
// 256 blocks, tile 16m x 128n, BK=64. E1/E2 = exp2(CSCALE*(h+bias)).
__global__ __launch_bounds__(256) void prep2_kernel(
    const float* __restrict__ x,
    const unsigned short* __restrict__ WhT, const unsigned short* __restrict__ WlT,
    const float* __restrict__ b1, const float* __restrict__ b2,
    float* __restrict__ E1, float* __restrict__ E2) {
    __shared__ unsigned short AsH[16][72];
    __shared__ unsigned short AsL[16][72];
    __shared__ unsigned short BsH[128][72];
    __shared__ unsigned short BsL[128][72];   // 41.6 KB
    int m0 = blockIdx.x << 4;
    int tid = threadIdx.x;
    int lane = tid & 63;
    int wv = tid >> 6;
    int wn = wv << 5;
    int l15 = lane & 15;
    int quad = lane >> 4;

    v4f acc[2];
    acc[0] = (v4f){0.f, 0.f, 0.f, 0.f};
    acc[1] = acc[0];

    for (int k0 = 0; k0 < DD; k0 += 64) {
        __syncthreads();
        // stage A: 16 rows x 64 k fp32 -> hi/lo. 256 float4 slots, 1 per thread.
        {
            int row = tid >> 4, k4 = (tid & 15) << 2;
            float4 v = *(const float4*)(x + (size_t)(m0 + row) * DD + k0 + k4);
            unsigned short h0, h1, h2, h3, l0, l1, l2, l3;
            split2(v.x, h0, l0); split2(v.y, h1, l1);
            split2(v.z, h2, l2); split2(v.w, h3, l3);
            uint2 hw, lw;
            hw.x = h0 | ((unsigned)h1 << 16); hw.y = h2 | ((unsigned)h3 << 16);
            lw.x = l0 | ((unsigned)l1 << 16); lw.y = l2 | ((unsigned)l3 << 16);
            *(uint2*)&AsH[row][k4] = hw;
            *(uint2*)&AsL[row][k4] = lw;
        }
        // stage B: 128 rows x 64 k bf16 hi/lo, 1024 uint4 slots, 4 per thread.
        #pragma unroll
        for (int i = 0; i < 4; i++) {
            int s = (i << 8) + tid;
            int row = s >> 3, k8 = (s & 7) << 3;
            *(uint4*)&BsH[row][k8] = *(const uint4*)(WhT + (size_t)row * DD + k0 + k8);
            *(uint4*)&BsL[row][k8] = *(const uint4*)(WlT + (size_t)row * DD + k0 + k8);
        }
        __syncthreads();
        #pragma unroll
        for (int kk = 0; kk < 64; kk += 32) {
            int kc = kk + (quad << 3);
            v8s aH0 = *(const v8s*)&AsH[l15][kc];
            v8s aL0 = *(const v8s*)&AsL[l15][kc];
            #pragma unroll
            for (int nt = 0; nt < 2; nt++) {
                v8s bH = *(const v8s*)&BsH[wn + (nt << 4) + l15][kc];
                v8s bL = *(const v8s*)&BsL[wn + (nt << 4) + l15][kc];
                acc[nt] = __builtin_amdgcn_mfma_f32_16x16x32_bf16(aH0, bH, acc[nt], 0, 0, 0);
                acc[nt] = __builtin_amdgcn_mfma_f32_16x16x32_bf16(aH0, bL, acc[nt], 0, 0, 0);
                acc[nt] = __builtin_amdgcn_mfma_f32_16x16x32_bf16(aL0, bH, acc[nt], 0, 0, 0);
            }
        }
    }
    #pragma unroll
    for (int nt = 0; nt < 2; nt++) {
        int n = wn + (nt << 4) + l15;     // 0..127
        int p = n & 63;
        float bias = (n < 64) ? b1[p] : b2[p];
        float* E = (n < 64) ? E1 : E2;
        int rbase = m0 + (quad << 2);
        #pragma unroll
        for (int r = 0; r < 4; r++) {
            float h = acc[nt][r] + bias;
            E[(size_t)(rbase + r) * PP + p] = __builtin_amdgcn_exp2f(h * CSCALE);
        }
    }
}

// scores: block = (b, 8 t rows) — 512 blocks (was 4 rows/1024 blocks). Each
// E2 read and each butterfly shfl now serves 8 output rows (loads/output and
// L2 traffic halved: 268 -> 134 MB). Thread: pp=tid&7 owns row t0+pp; uu=tid>>3
// is the u slot. Tree packed as v2f across row pairs (v_pk_fma_f32). One
// v_rcp_f32 per 8 p-terms (exact rational combine). own[32] in registers,
// deferred softmax. __launch_bounds__(256,2): 512 blocks = 2 blocks/CU; 256
// VGPR cap fits the ~150-reg live set (Hp[4][8] v2f + own[32]) without spill.
__global__ __launch_bounds__(256, 2) void scores_kernel(
    const float* __restrict__ E1, const float* __restrict__ E2,
    const float* __restrict__ E3, const float* __restrict__ wa_w,
    const float* __restrict__ wa_b, unsigned short* __restrict__ at_bf) {
    __shared__ float sm[4][8];
    __shared__ float sl[4][8];
    int tid = threadIdx.x;
    int bid = blockIdx.x;
    int b = bid >> 7;
    int t0 = (bid & 127) << 3;
    int pp = tid & 7;
    int uu = tid >> 3;           // 0..31
    int p0 = pp << 3;
    int lane = tid & 63;
    int wv = tid >> 6;
    bool pb0 = (pp & 1) != 0;
    bool pb1 = (pp & 2) != 0;
    bool pb2 = (pp & 4) != 0;

    v2f ww2p[8];                 // {w_j, w_j} broadcast pairs
    v2f Hp[4][8];                // [row-pair][j]: {H[2q][j], H[2q+1][j]}
    float base;
    {
        float4 wv0 = *(const float4*)(wa_w + p0);
        float4 wv1 = *(const float4*)(wa_w + p0 + 4);
        float s = wv0.x + wv0.y + wv0.z + wv0.w + wv1.x + wv1.y + wv1.z + wv1.w;
        s += __shfl_xor(s, 1, 64);
        s += __shfl_xor(s, 2, 64);
        s += __shfl_xor(s, 4, 64);
        base = (s + wa_b[0]) * L2E;
        float ww2[8];
        ww2[0] = -2.f * L2E * wv0.x; ww2[1] = -2.f * L2E * wv0.y;
        ww2[2] = -2.f * L2E * wv0.z; ww2[3] = -2.f * L2E * wv0.w;
        ww2[4] = -2.f * L2E * wv1.x; ww2[5] = -2.f * L2E * wv1.y;
        ww2[6] = -2.f * L2E * wv1.z; ww2[7] = -2.f * L2E * wv1.w;
        #pragma unroll
        for (int j = 0; j < 8; j++) ww2p[j] = (v2f){ww2[j], ww2[j]};
        float4 e3a = *(const float4*)(E3 + (b << 6) + p0);
        float4 e3b = *(const float4*)(E3 + (b << 6) + p0 + 4);
        float e3[8] = {e3a.x, e3a.y, e3a.z, e3a.w, e3b.x, e3b.y, e3b.z, e3b.w};
        #pragma unroll
        for (int q = 0; q < 4; q++) {
            const float* r0p = E1 + (((size_t)(b << 10) + t0 + 2 * q) << 6) + p0;
            const float* r1p = r0p + PP;
            float4 a0 = *(const float4*)r0p;
            float4 a1 = *(const float4*)(r0p + 4);
            float4 c0 = *(const float4*)r1p;
            float4 c1 = *(const float4*)(r1p + 4);
            float r0v[8] = {a0.x, a0.y, a0.z, a0.w, a1.x, a1.y, a1.z, a1.w};
            float r1v[8] = {c0.x, c0.y, c0.z, c0.w, c1.x, c1.y, c1.z, c1.w};
            #pragma unroll
            for (int j = 0; j < 8; j++)
                Hp[q][j] = (v2f){r0v[j] * e3[j], r1v[j] * e3[j]};
        }
    }
    const v2f one2 = (v2f){1.0f, 1.0f};

    float own[32];
    float mown = -1e30f;
    #pragma unroll
    for (int k = 0; k < 32; k++) {
        int u = (k << 5) + uu;
        const float* ep = E2 + (((size_t)(b << 10) + u) << 6) + p0;
        float4 e0 = *(const float4*)ep;
        float4 e1 = *(const float4*)(ep + 4);
        v2f evp[8];
        evp[0] = (v2f){e0.x, e0.x}; evp[1] = (v2f){e0.y, e0.y};
        evp[2] = (v2f){e0.z, e0.z}; evp[3] = (v2f){e0.w, e0.w};
        evp[4] = (v2f){e1.x, e1.x}; evp[5] = (v2f){e1.y, e1.y};
        evp[6] = (v2f){e1.z, e1.z}; evp[7] = (v2f){e1.w, e1.w};
        float sr_[8];
        #pragma unroll
        for (int q = 0; q < 4; q++) {
            v2f d0 = pfma(Hp[q][0], evp[0], one2);
            v2f d1 = pfma(Hp[q][1], evp[1], one2);
            v2f d2 = pfma(Hp[q][2], evp[2], one2);
            v2f d3 = pfma(Hp[q][3], evp[3], one2);
            v2f d4 = pfma(Hp[q][4], evp[4], one2);
            v2f d5 = pfma(Hp[q][5], evp[5], one2);
            v2f d6 = pfma(Hp[q][6], evp[6], one2);
            v2f d7 = pfma(Hp[q][7], evp[7], one2);
            v2f e01 = d0 * d1, e23 = d2 * d3, e45 = d4 * d5, e67 = d6 * d7;
            v2f n01 = pfma(ww2p[0], d1, ww2p[1] * d0);
            v2f n23 = pfma(ww2p[2], d3, ww2p[3] * d2);
            v2f n45 = pfma(ww2p[4], d5, ww2p[5] * d4);
            v2f n67 = pfma(ww2p[6], d7, ww2p[7] * d6);
            v2f q03 = e01 * e23, q47 = e45 * e67;
            v2f n03 = pfma(n23, e01, n01 * e23);
            v2f n47 = pfma(n67, e45, n45 * e67);
            v2f Dq = q03 * q47;
            v2f Nq = pfma(n47, q03, n03 * q47);
            sr_[2 * q]     = Nq.x * __builtin_amdgcn_rcpf(Dq.x);
            sr_[2 * q + 1] = Nq.y * __builtin_amdgcn_rcpf(Dq.y);
        }
        // 8->1 butterfly over pp lanes (7 shfls), row identity follows pp bits.
        float a0 = pb2 ? sr_[4] : sr_[0];
        float a1 = pb2 ? sr_[5] : sr_[1];
        float a2 = pb2 ? sr_[6] : sr_[2];
        float a3 = pb2 ? sr_[7] : sr_[3];
        float o0 = pb2 ? sr_[0] : sr_[4];
        float o1 = pb2 ? sr_[1] : sr_[5];
        float o2 = pb2 ? sr_[2] : sr_[6];
        float o3 = pb2 ? sr_[3] : sr_[7];
        a0 += __shfl_xor(o0, 4, 64);
        a1 += __shfl_xor(o1, 4, 64);
        a2 += __shfl_xor(o2, 4, 64);
        a3 += __shfl_xor(o3, 4, 64);
        float b0v = pb1 ? a2 : a0;
        float b1v = pb1 ? a3 : a1;
        float t0_ = pb1 ? a0 : a2;
        float t1_ = pb1 ? a1 : a3;
        b0v += __shfl_xor(t0_, 2, 64);
        b1v += __shfl_xor(t1_, 2, 64);
        float c0 = pb0 ? b1v : b0v;
        float c1 = pb0 ? b0v : b1v;
        c0 += __shfl_xor(c1, 1, 64);
        float o = c0 + base;
        own[k] = o;
        mown = fmaxf(mown, o);
    }
    // max over uu: in-wave lanes with same pp (xor 8,16,32), then across waves.
    mown = fmaxf(mown, __shfl_xor(mown, 8, 64));
    mown = fmaxf(mown, __shfl_xor(mown, 16, 64));
    mown = fmaxf(mown, __shfl_xor(mown, 32, 64));
    if (lane < 8) sm[wv][lane] = mown;
    __syncthreads();
    float mx = fmaxf(fmaxf(sm[0][pp], sm[1][pp]), fmaxf(sm[2][pp], sm[3][pp]));

    float l = 0.f;
    #pragma unroll
    for (int k = 0; k < 32; k++) {
        float e = __builtin_amdgcn_exp2f(own[k] - mx);
        own[k] = e;
        l += e;
    }
    l += __shfl_xor(l, 8, 64);
    l += __shfl_xor(l, 16, 64);
    l += __shfl_xor(l, 32, 64);
    if (lane < 8) sl[wv][lane] = l;
    __syncthreads();
    float inv = 1.0f / (sl[0][pp] + sl[1][pp] + sl[2][pp] + sl[3][pp]);

    {
        size_t rowbase = ((size_t)((b << 10) + t0 + pp)) << 10;
        #pragma unroll
        for (int k = 0; k < 32; k++) {
            at_bf[rowbase + (k << 5) + uu] = f2bf(own[k] * inv);
        }
    }
}

// av: out[b] = at_bf[b] (1024x1024 bf16) @ Xt[b]^T via MFMA. 64x64 tile, BK=64.
// Staging via global_load_lds width=16 (DMA, no ds_write pipe cost). LDS tiles
// unpadded [64][64]; column chunks XOR-swizzled by (row&7) at the GLOBAL source
// so fragment ds_read_b128 is 2-way (free) bank access.
__global__ __launch_bounds__(256) void av_mfma_kernel(
    const unsigned short* __restrict__ at_bf, const unsigned short* __restrict__ xt,
    float* __restrict__ out) {
    __shared__ unsigned short As[64 * 64];  // 8 KB
    __shared__ unsigned short Bs[64 * 64];  // 8 KB
    int b = blockIdx.z;
    int m0 = blockIdx.y << 6;
    int n0 = blockIdx.x << 6;
    const unsigned short* A = at_bf + ((size_t)b << 20);
    const unsigned short* Bt = xt + (size_t)b * DD * TT;
    int tid = threadIdx.x;
    int lane = tid & 63;
    int wv = tid >> 6;
    int wm = (wv & 1) << 5;
    int wn = (wv >> 1) << 5;
    int l15 = lane & 15;
    int quad = lane >> 4;

    int sr = lane >> 3;           // 0..7 relative row within wave-instr
    int scg = (lane & 7) ^ sr;    // swizzled source chunk

    v4f acc00 = {0.f, 0.f, 0.f, 0.f}, acc01 = acc00, acc10 = acc00, acc11 = acc00;

    for (int k0 = 0; k0 < TT; k0 += 64) {
        __syncthreads();
        #pragma unroll
        for (int t = 0; t < 2; t++) {
            int r0 = (wv << 4) + (t << 3);    // wave-uniform row base, 8 rows/instr
            int row = r0 + sr;
            gld_lds16(A + (size_t)(m0 + row) * TT + k0 + (scg << 3), &As[r0 << 6]);
            gld_lds16(Bt + (size_t)(n0 + row) * TT + k0 + (scg << 3), &Bs[r0 << 6]);
        }
        __syncthreads();
        #pragma unroll
        for (int kq = 0; kq < 2; kq++) {
            int c = (kq << 2) + quad;
            int swz = (c ^ (l15 & 7)) << 3;
            v8s a0 = *(const v8s*)&As[((wm + l15) << 6) + swz];
            v8s a1 = *(const v8s*)&As[((wm + 16 + l15) << 6) + swz];
            v8s b0 = *(const v8s*)&Bs[((wn + l15) << 6) + swz];
            v8s b1 = *(const v8s*)&Bs[((wn + 16 + l15) << 6) + swz];
            acc00 = __builtin_amdgcn_mfma_f32_16x16x32_bf16(a0, b0, acc00, 0, 0, 0);
            acc01 = __builtin_amdgcn_mfma_f32_16x16x32_bf16(a0, b1, acc01, 0, 0, 0);
            acc10 = __builtin_amdgcn_mfma_f32_16x16x32_bf16(a1, b0, acc10, 0, 0, 0);
            acc11 = __builtin_amdgcn_mfma_f32_16x16x32_bf16(a1, b1, acc11, 0, 0, 0);
        }
    }
    float* C = out + (size_t)b * TT * DD;
    int rbase = m0 + wm + (quad << 2);
    int cn = n0 + wn + l15;
    #pragma unroll
    for (int r = 0; r < 4; r++) {
        C[(size_t)(rbase + r) * DD + cn]           = acc00[r];
        C[(size_t)(rbase + r) * DD + cn + 16]      = acc01[r];
        C[(size_t)(rbase + 16 + r) * DD + cn]      = acc10[r];
        C[(size_t)(rbase + 16 + r) * DD + cn + 16] = acc11[r];
    }
}

extern "C" void kernel_launch(void* const* d_in, const int* in_sizes, int n_in,
                              void* d_out, int out_size, void* d_ws, size_t ws_size,
                              hipStream_t stream) {
    const float* inputs = (const float*)d_in[0];
    const float* ec     = (const float*)d_in[1];
    const float* W1     = (const float*)d_in[2];
    const float* b1     = (const float*)d_in[3];
    const float* W2     = (const float*)d_in[4];
    const float* b2     = (const float*)d_in[5];
    const float* W3     = (const float*)d_in[6];
    const float* b3     = (const float*)d_in[7];
    const float* wa_w   = (const float*)d_in[8];
    const float* wa_b   = (const float*)d_in[9];
    float* out = (float*)d_out;

    // ws layout (float units) — R5/R7-proven 14,682,112-byte footprint:
    //   E1[262144] | E2[262144] | E3[512] | at_bf (2097152 f) | xt (1048576 f)
    // WhT/WlT alias the front of at_bf (live range prep1->prep2 only).
    float* ws = (float*)d_ws;
    float* E1 = ws;
    float* E2 = ws + 262144;
    float* E3 = ws + 524288;
    unsigned short* at_bf = (unsigned short*)(ws + 524800);
    unsigned short* xt    = (unsigned short*)(ws + 524800 + 2097152);
    unsigned short* WhT   = at_bf;            // 65536 shorts
    unsigned short* WlT   = at_bf + 65536;    // 65536 shorts

    hipLaunchKernelGGL(prep1_kernel, dim3(529), dim3(256), 0, stream,
                       inputs, ec, W1, W2, W3, b3, xt, WhT, WlT, E3);
    hipLaunchKernelGGL(prep2_kernel, dim3(256), dim3(256), 0, stream,
                       inputs, WhT, WlT, b1, b2, E1, E2);
    hipLaunchKernelGGL(scores_kernel, dim3(512), dim3(256), 0, stream,
                       E1, E2, E3, wa_w, wa_b, at_bf);
    hipLaunchKernelGGL(av_mfma_kernel, dim3(DD / 64, TT / 64, BB), dim3(256), 0, stream,
                       at_bf, xt, out);
}

// Round 8
// 144.500 us; speedup vs baseline: 1.0068x; 1.0068x over previous
//
#include <hip/hip_runtime.h>
#include <hip/hip_bf16.h>

constexpr int BB = 4;
constexpr int TT = 1024;
constexpr int DD = 512;
constexpr int PP = 64;
constexpr int MM = 256;

constexpr float CSCALE = 2.8853900817779268f; // 2*log2(e)
constexpr float L2E = 1.4426950408889634f;    // log2(e)

typedef __attribute__((ext_vector_type(8))) short v8s;
typedef __attribute__((ext_vector_type(4))) float v4f;
typedef __attribute__((ext_vector_type(2))) float v2f;
typedef unsigned int __attribute__((address_space(1))) gu32;
typedef unsigned int __attribute__((address_space(3))) su32;

__device__ __forceinline__ unsigned short f2bf(float f) {
    unsigned u = __builtin_bit_cast(unsigned, f);
    unsigned r = (u + 0x7fffu + ((u >> 16) & 1u)) >> 16;
    return (unsigned short)r;
}
__device__ __forceinline__ float bf2f(unsigned short h) {
    return __builtin_bit_cast(float, (unsigned)h << 16);
}
__device__ __forceinline__ void split2(float v, unsigned short& h, unsigned short& l) {
    unsigned short hh = f2bf(v);
    h = hh;
    l = f2bf(v - bf2f(hh));
}
__device__ __forceinline__ void gld_lds16(const void* g, void* l) {
    __builtin_amdgcn_global_load_lds((const gu32*)g, (su32*)l, 16, 0, 0);
}
__device__ __forceinline__ v2f pfma(v2f a, v2f b, v2f c) {
    return __builtin_elementwise_fma(a, b, c);   // -> v_pk_fma_f32 on gfx950
}

// prep1s: 17 blocks. [0,16): W1|W2 -> WhT/WlT (bf16 hi/lo, [n][k] transposed);
//         16: ec@W3 -> E3. Tiny kernel (~2 us) — the 512-block xt transpose
//         moved into prep2x where it overlaps the 1-block/CU GEMM.
__global__ __launch_bounds__(256) void prep1s_kernel(
    const float* __restrict__ ec,
    const float* __restrict__ W1, const float* __restrict__ W2,
    const float* __restrict__ W3, const float* __restrict__ b3,
    unsigned short* __restrict__ WhT, unsigned short* __restrict__ WlT,
    float* __restrict__ E3) {
    int bid = blockIdx.x;
    int tid = threadIdx.x;
    if (bid < 16) {
        // W transpose: block w covers k-slice [w*32, w*32+32), all 128 n.
        int w = bid;
        int n = tid >> 1;               // 0..127
        int kb = (w << 5) + ((tid & 1) << 4);
        unsigned short hs[16], ls[16];
        #pragma unroll
        for (int kk = 0; kk < 16; kk++) {
            int k = kb + kk;
            float v = (n < 64) ? W1[k * PP + n] : W2[k * PP + (n - 64)];
            split2(v, hs[kk], ls[kk]);
        }
        uint4 a, bqq;
        a.x = hs[0] | ((unsigned)hs[1] << 16);   a.y = hs[2] | ((unsigned)hs[3] << 16);
        a.z = hs[4] | ((unsigned)hs[5] << 16);   a.w = hs[6] | ((unsigned)hs[7] << 16);
        bqq.x = hs[8] | ((unsigned)hs[9] << 16); bqq.y = hs[10] | ((unsigned)hs[11] << 16);
        bqq.z = hs[12] | ((unsigned)hs[13] << 16); bqq.w = hs[14] | ((unsigned)hs[15] << 16);
        *(uint4*)(WhT + (size_t)n * DD + kb) = a;
        *(uint4*)(WhT + (size_t)n * DD + kb + 8) = bqq;
        a.x = ls[0] | ((unsigned)ls[1] << 16);   a.y = ls[2] | ((unsigned)ls[3] << 16);
        a.z = ls[4] | ((unsigned)ls[5] << 16);   a.w = ls[6] | ((unsigned)ls[7] << 16);
        bqq.x = ls[8] | ((unsigned)ls[9] << 16); bqq.y = ls[10] | ((unsigned)ls[11] << 16);
        bqq.z = ls[12] | ((unsigned)ls[13] << 16); bqq.w = ls[14] | ((unsigned)ls[15] << 16);
        *(uint4*)(WlT + (size_t)n * DD + kb) = a;
        *(uint4*)(WlT + (size_t)n * DD + kb + 8) = bqq;
    } else {
        int b = tid >> 6, p = tid & 63;
        float a = b3[p];
        const float* e = ec + (size_t)b * MM;
        #pragma unroll 4
        for (int m = 0; m < MM; m++) a = fmaf(e[m], W3[m * PP + p], a);
        E3[b * PP + p] = __builtin_amdgcn_exp2f(a * CSCALE);
    }
}

// prep2x: 768 blocks. [0,256): proj GEMM h = x (4096x512) @ [W1|W2] (512x128)
// via 3-term bf16-split MFMA, tile 16m x 128n, BK=64, E1/E2 = exp2(CSCALE*(h+b)).
// [256,768): x tiles -> xt (bf16 transpose) — independent work that overlaps the
// 1-block/CU GEMM (46 KB LDS union = 3 blocks/CU, grid exactly fills 256 CUs x3).
__global__ __launch_bounds__(256) void prep2x_kernel(
    const float* __restrict__ x,
    const unsigned short* __restrict__ WhT, const unsigned short* __restrict__ WlT,
    const float* __restrict__ b1, const float* __restrict__ b2,
    float* __restrict__ E1, float* __restrict__ E2,
    unsigned short* __restrict__ xt) {
    __shared__ __align__(16) char smem[46080];
    int bid = blockIdx.x;
    int tid = threadIdx.x;
    if (bid < 256) {
        struct P2 {
            unsigned short AsH[16][72], AsL[16][72];
            unsigned short BsH[128][72], BsL[128][72];
        };
        P2& S = *(P2*)smem;
        int m0 = bid << 4;
        int lane = tid & 63;
        int wv = tid >> 6;
        int wn = wv << 5;
        int l15 = lane & 15;
        int quad = lane >> 4;

        v4f acc[2];
        acc[0] = (v4f){0.f, 0.f, 0.f, 0.f};
        acc[1] = acc[0];

        for (int k0 = 0; k0 < DD; k0 += 64) {
            __syncthreads();
            // stage A: 16 rows x 64 k fp32 -> hi/lo. 256 float4 slots, 1/thread.
            {
                int row = tid >> 4, k4 = (tid & 15) << 2;
                float4 v = *(const float4*)(x + (size_t)(m0 + row) * DD + k0 + k4);
                unsigned short h0, h1, h2, h3, l0, l1, l2, l3;
                split2(v.x, h0, l0); split2(v.y, h1, l1);
                split2(v.z, h2, l2); split2(v.w, h3, l3);
                uint2 hw, lw;
                hw.x = h0 | ((unsigned)h1 << 16); hw.y = h2 | ((unsigned)h3 << 16);
                lw.x = l0 | ((unsigned)l1 << 16); lw.y = l2 | ((unsigned)l3 << 16);
                *(uint2*)&S.AsH[row][k4] = hw;
                *(uint2*)&S.AsL[row][k4] = lw;
            }
            // stage B: 128 rows x 64 k bf16 hi/lo, 1024 uint4 slots, 4/thread.
            #pragma unroll
            for (int i = 0; i < 4; i++) {
                int s = (i << 8) + tid;
                int row = s >> 3, k8 = (s & 7) << 3;
                *(uint4*)&S.BsH[row][k8] = *(const uint4*)(WhT + (size_t)row * DD + k0 + k8);
                *(uint4*)&S.BsL[row][k8] = *(const uint4*)(WlT + (size_t)row * DD + k0 + k8);
            }
            __syncthreads();
            #pragma unroll
            for (int kk = 0; kk < 64; kk += 32) {
                int kc = kk + (quad << 3);
                v8s aH0 = *(const v8s*)&S.AsH[l15][kc];
                v8s aL0 = *(const v8s*)&S.AsL[l15][kc];
                #pragma unroll
                for (int nt = 0; nt < 2; nt++) {
                    v8s bH = *(const v8s*)&S.BsH[wn + (nt << 4) + l15][kc];
                    v8s bL = *(const v8s*)&S.BsL[wn + (nt << 4) + l15][kc];
                    acc[nt] = __builtin_amdgcn_mfma_f32_16x16x32_bf16(aH0, bH, acc[nt], 0, 0, 0);
                    acc[nt] = __builtin_amdgcn_mfma_f32_16x16x32_bf16(aH0, bL, acc[nt], 0, 0, 0);
                    acc[nt] = __builtin_amdgcn_mfma_f32_16x16x32_bf16(aL0, bH, acc[nt], 0, 0, 0);
                }
            }
        }
        #pragma unroll
        for (int nt = 0; nt < 2; nt++) {
            int n = wn + (nt << 4) + l15;     // 0..127
            int p = n & 63;
            float bias = (n < 64) ? b1[p] : b2[p];
            float* E = (n < 64) ? E1 : E2;
            int rbase = m0 + (quad << 2);
            #pragma unroll
            for (int r = 0; r < 4; r++) {
                float h = acc[nt][r] + bias;
                E[(size_t)(rbase + r) * PP + p] = __builtin_amdgcn_exp2f(h * CSCALE);
            }
        }
    } else {
        // xt transpose: tbid in [0,512), tile 64u x 64d of batch b.
        float (*tile)[65] = (float(*)[65])smem;
        int tbid = bid - 256;
        int d0 = (tbid & 7) << 6;
        int u0 = ((tbid >> 3) & 15) << 6;
        int b = tbid >> 7;
        int c4 = (tid & 15) << 2, r = tid >> 4;
        #pragma unroll
        for (int i = 0; i < 4; i++) {
            int row = r + (i << 4);
            float4 v = *(const float4*)(x + ((size_t)b * TT + u0 + row) * DD + d0 + c4);
            tile[row][c4 + 0] = v.x;
            tile[row][c4 + 1] = v.y;
            tile[row][c4 + 2] = v.z;
            tile[row][c4 + 3] = v.w;
        }
        __syncthreads();
        int dd = tid >> 2;
        int uq = (tid & 3) << 4;
        unsigned short us[16];
        #pragma unroll
        for (int j = 0; j < 16; j++) us[j] = f2bf(tile[uq + j][dd]);
        uint4 w0, w1;
        w0.x = us[0] | ((unsigned)us[1] << 16);  w0.y = us[2] | ((unsigned)us[3] << 16);
        w0.z = us[4] | ((unsigned)us[5] << 16);  w0.w = us[6] | ((unsigned)us[7] << 16);
        w1.x = us[8] | ((unsigned)us[9] << 16);  w1.y = us[10] | ((unsigned)us[11] << 16);
        w1.z = us[12] | ((unsigned)us[13] << 16); w1.w = us[14] | ((unsigned)us[15] << 16);
        unsigned short* dst = xt + ((size_t)b * DD + d0 + dd) * TT + u0 + uq;
        *(uint4*)dst = w0;
        *(uint4*)(dst + 8) = w1;
    }
}

// scores: block = (b, 8 t rows), 512 blocks. pp=tid&7 owns row t0+pp; uu=tid>>3
// is the u slot. Tree packed as v2f across row pairs (v_pk_fma_f32); one
// v_rcp_f32 per 8 p-terms (exact rational combine). own[32] in registers,
// deferred softmax. __launch_bounds__(256,2): 512 blocks = 2 blocks/CU.
__global__ __launch_bounds__(256, 2) void scores_kernel(
    const float* __restrict__ E1, const float* __restrict__ E2,
    const float* __restrict__ E3, const float* __restrict__ wa_w,
    const float* __restrict__ wa_b, unsigned short* __restrict__ at_bf) {
    __shared__ float sm[4][8];
    __shared__ float sl[4][8];
    int tid = threadIdx.x;
    int bid = blockIdx.x;
    int b = bid >> 7;
    int t0 = (bid & 127) << 3;
    int pp = tid & 7;
    int uu = tid >> 3;           // 0..31
    int p0 = pp << 3;
    int lane = tid & 63;
    int wv = tid >> 6;
    bool pb0 = (pp & 1) != 0;
    bool pb1 = (pp & 2) != 0;
    bool pb2 = (pp & 4) != 0;

    v2f ww2p[8];                 // {w_j, w_j} broadcast pairs
    v2f Hp[4][8];                // [row-pair][j]: {H[2q][j], H[2q+1][j]}
    float base;
    {
        float4 wv0 = *(const float4*)(wa_w + p0);
        float4 wv1 = *(const float4*)(wa_w + p0 + 4);
        float s = wv0.x + wv0.y + wv0.z + wv0.w + wv1.x + wv1.y + wv1.z + wv1.w;
        s += __shfl_xor(s, 1, 64);
        s += __shfl_xor(s, 2, 64);
        s += __shfl_xor(s, 4, 64);
        base = (s + wa_b[0]) * L2E;
        float ww2[8];
        ww2[0] = -2.f * L2E * wv0.x; ww2[1] = -2.f * L2E * wv0.y;
        ww2[2] = -2.f * L2E * wv0.z; ww2[3] = -2.f * L2E * wv0.w;
        ww2[4] = -2.f * L2E * wv1.x; ww2[5] = -2.f * L2E * wv1.y;
        ww2[6] = -2.f * L2E * wv1.z; ww2[7] = -2.f * L2E * wv1.w;
        #pragma unroll
        for (int j = 0; j < 8; j++) ww2p[j] = (v2f){ww2[j], ww2[j]};
        float4 e3a = *(const float4*)(E3 + (b << 6) + p0);
        float4 e3b = *(const float4*)(E3 + (b << 6) + p0 + 4);
        float e3[8] = {e3a.x, e3a.y, e3a.z, e3a.w, e3b.x, e3b.y, e3b.z, e3b.w};
        #pragma unroll
        for (int q = 0; q < 4; q++) {
            const float* r0p = E1 + (((size_t)(b << 10) + t0 + 2 * q) << 6) + p0;
            const float* r1p = r0p + PP;
            float4 a0 = *(const float4*)r0p;
            float4 a1 = *(const float4*)(r0p + 4);
            float4 c0 = *(const float4*)r1p;
            float4 c1 = *(const float4*)(r1p + 4);
            float r0v[8] = {a0.x, a0.y, a0.z, a0.w, a1.x, a1.y, a1.z, a1.w};
            float r1v[8] = {c0.x, c0.y, c0.z, c0.w, c1.x, c1.y, c1.z, c1.w};
            #pragma unroll
            for (int j = 0; j < 8; j++)
                Hp[q][j] = (v2f){r0v[j] * e3[j], r1v[j] * e3[j]};
        }
    }
    const v2f one2 = (v2f){1.0f, 1.0f};

    float own[32];
    float mown = -1e30f;
    #pragma unroll
    for (int k = 0; k < 32; k++) {
        int u = (k << 5) + uu;
        const float* ep = E2 + (((size_t)(b << 10) + u) << 6) + p0;
        float4 e0 = *(const float4*)ep;
        float4 e1 = *(const float4*)(ep + 4);
        v2f evp[8];
        evp[0] = (v2f){e0.x, e0.x}; evp[1] = (v2f){e0.y, e0.y};
        evp[2] = (v2f){e0.z, e0.z}; evp[3] = (v2f){e0.w, e0.w};
        evp[4] = (v2f){e1.x, e1.x}; evp[5] = (v2f){e1.y, e1.y};
        evp[6] = (v2f){e1.z, e1.z}; evp[7] = (v2f){e1.w, e1.w};
        float sr_[8];
        #pragma unroll
        for (int q = 0; q < 4; q++) {
            v2f d0 = pfma(Hp[q][0], evp[0], one2);
            v2f d1 = pfma(Hp[q][1], evp[1], one2);
            v2f d2 = pfma(Hp[q][2], evp[2], one2);
            v2f d3 = pfma(Hp[q][3], evp[3], one2);
            v2f d4 = pfma(Hp[q][4], evp[4], one2);
            v2f d5 = pfma(Hp[q][5], evp[5], one2);
            v2f d6 = pfma(Hp[q][6], evp[6], one2);
            v2f d7 = pfma(Hp[q][7], evp[7], one2);
            v2f e01 = d0 * d1, e23 = d2 * d3, e45 = d4 * d5, e67 = d6 * d7;
            v2f n01 = pfma(ww2p[0], d1, ww2p[1] * d0);
            v2f n23 = pfma(ww2p[2], d3, ww2p[3] * d2);
            v2f n45 = pfma(ww2p[4], d5, ww2p[5] * d4);
            v2f n67 = pfma(ww2p[6], d7, ww2p[7] * d6);
            v2f q03 = e01 * e23, q47 = e45 * e67;
            v2f n03 = pfma(n23, e01, n01 * e23);
            v2f n47 = pfma(n67, e45, n45 * e67);
            v2f Dq = q03 * q47;
            v2f Nq = pfma(n47, q03, n03 * q47);
            sr_[2 * q]     = Nq.x * __builtin_amdgcn_rcpf(Dq.x);
            sr_[2 * q + 1] = Nq.y * __builtin_amdgcn_rcpf(Dq.y);
        }
        // 8->1 butterfly over pp lanes (7 shfls), row identity follows pp bits.
        float a0 = pb2 ? sr_[4] : sr_[0];
        float a1 = pb2 ? sr_[5] : sr_[1];
        float a2 = pb2 ? sr_[6] : sr_[2];
        float a3 = pb2 ? sr_[7] : sr_[3];
        float o0 = pb2 ? sr_[0] : sr_[4];
        float o1 = pb2 ? sr_[1] : sr_[5];
        float o2 = pb2 ? sr_[2] : sr_[6];
        float o3 = pb2 ? sr_[3] : sr_[7];
        a0 += __shfl_xor(o0, 4, 64);
        a1 += __shfl_xor(o1, 4, 64);
        a2 += __shfl_xor(o2, 4, 64);
        a3 += __shfl_xor(o3, 4, 64);
        float b0v = pb1 ? a2 : a0;
        float b1v = pb1 ? a3 : a1;
        float t0_ = pb1 ? a0 : a2;
        float t1_ = pb1 ? a1 : a3;
        b0v += __shfl_xor(t0_, 2, 64);
        b1v += __shfl_xor(t1_, 2, 64);
        float c0 = pb0 ? b1v : b0v;
        float c1 = pb0 ? b0v : b1v;
        c0 += __shfl_xor(c1, 1, 64);
        float o = c0 + base;
        own[k] = o;
        mown = fmaxf(mown, o);
    }
    // max over uu: in-wave lanes with same pp (xor 8,16,32), then across waves.
    mown = fmaxf(mown, __shfl_xor(mown, 8, 64));
    mown = fmaxf(mown, __shfl_xor(mown, 16, 64));
    mown = fmaxf(mown, __shfl_xor(mown, 32, 64));
    if (lane < 8) sm[wv][lane] = mown;
    __syncthreads();
    float mx = fmaxf(fmaxf(sm[0][pp], sm[1][pp]), fmaxf(sm[2][pp], sm[3][pp]));

    float l = 0.f;
    #pragma unroll
    for (int k = 0; k < 32; k++) {
        float e = __builtin_amdgcn_exp2f(own[k] - mx);
        own[k] = e;
        l += e;
    }
    l += __shfl_xor(l, 8, 64);
    l += __shfl_xor(l, 16, 64);
    l += __shfl_xor(l, 32, 64);
    if (lane < 8) sl[wv][lane] = l;
    __syncthreads();
    float inv = 1.0f / (sl[0][pp] + sl[1][pp] + sl[2][pp] + sl[3][pp]);

    {
        size_t rowbase = ((size_t)((b << 10) + t0 + pp)) << 10;
        #pragma unroll
        for (int k = 0; k < 32; k++) {
            at_bf[rowbase + (k << 5) + uu] = f2bf(own[k] * inv);
        }
    }
}

// av: out[b] = at_bf[b] (1024x1024 bf16) @ Xt[b]^T via MFMA. 64x64 tile, BK=64.
// Staging via global_load_lds width=16 (DMA, no ds_write pipe cost). LDS tiles
// unpadded [64][64]; column chunks XOR-swizzled by (row&7) at the GLOBAL source
// so fragment ds_read_b128 is 2-way (free) bank access.
__global__ __launch_bounds__(256) void av_mfma_kernel(
    const unsigned short* __restrict__ at_bf, const unsigned short* __restrict__ xt,
    float* __restrict__ out) {
    __shared__ unsigned short As[64 * 64];  // 8 KB
    __shared__ unsigned short Bs[64 * 64];  // 8 KB
    int b = blockIdx.z;
    int m0 = blockIdx.y << 6;
    int n0 = blockIdx.x << 6;
    const unsigned short* A = at_bf + ((size_t)b << 20);
    const unsigned short* Bt = xt + (size_t)b * DD * TT;
    int tid = threadIdx.x;
    int lane = tid & 63;
    int wv = tid >> 6;
    int wm = (wv & 1) << 5;
    int wn = (wv >> 1) << 5;
    int l15 = lane & 15;
    int quad = lane >> 4;

    int sr = lane >> 3;           // 0..7 relative row within wave-instr
    int scg = (lane & 7) ^ sr;    // swizzled source chunk

    v4f acc00 = {0.f, 0.f, 0.f, 0.f}, acc01 = acc00, acc10 = acc00, acc11 = acc00;

    for (int k0 = 0; k0 < TT; k0 += 64) {
        __syncthreads();
        #pragma unroll
        for (int t = 0; t < 2; t++) {
            int r0 = (wv << 4) + (t << 3);    // wave-uniform row base, 8 rows/instr
            int row = r0 + sr;
            gld_lds16(A + (size_t)(m0 + row) * TT + k0 + (scg << 3), &As[r0 << 6]);
            gld_lds16(Bt + (size_t)(n0 + row) * TT + k0 + (scg << 3), &Bs[r0 << 6]);
        }
        __syncthreads();
        #pragma unroll
        for (int kq = 0; kq < 2; kq++) {
            int c = (kq << 2) + quad;
            int swz = (c ^ (l15 & 7)) << 3;
            v8s a0 = *(const v8s*)&As[((wm + l15) << 6) + swz];
            v8s a1 = *(const v8s*)&As[((wm + 16 + l15) << 6) + swz];
            v8s b0 = *(const v8s*)&Bs[((wn + l15) << 6) + swz];
            v8s b1 = *(const v8s*)&Bs[((wn + 16 + l15) << 6) + swz];
            acc00 = __builtin_amdgcn_mfma_f32_16x16x32_bf16(a0, b0, acc00, 0, 0, 0);
            acc01 = __builtin_amdgcn_mfma_f32_16x16x32_bf16(a0, b1, acc01, 0, 0, 0);
            acc10 = __builtin_amdgcn_mfma_f32_16x16x32_bf16(a1, b0, acc10, 0, 0, 0);
            acc11 = __builtin_amdgcn_mfma_f32_16x16x32_bf16(a1, b1, acc11, 0, 0, 0);
        }
    }
    float* C = out + (size_t)b * TT * DD;
    int rbase = m0 + wm + (quad << 2);
    int cn = n0 + wn + l15;
    #pragma unroll
    for (int r = 0; r < 4; r++) {
        C[(size_t)(rbase + r) * DD + cn]           = acc00[r];
        C[(size_t)(rbase + r) * DD + cn + 16]      = acc01[r];
        C[(size_t)(rbase + 16 + r) * DD + cn]      = acc10[r];
        C[(size_t)(rbase + 16 + r) * DD + cn + 16] = acc11[r];
    }
}

extern "C" void kernel_launch(void* const* d_in, const int* in_sizes, int n_in,
                              void* d_out, int out_size, void* d_ws, size_t ws_size,
                              hipStream_t stream) {
    const float* inputs = (const float*)d_in[0];
    const float* ec     = (const float*)d_in[1];
    const float* W1     = (const float*)d_in[2];
    const float* b1     = (const float*)d_in[3];
    const float* W2     = (const float*)d_in[4];
    const float* b2     = (const float*)d_in[5];
    const float* W3     = (const float*)d_in[6];
    const float* b3     = (const float*)d_in[7];
    const float* wa_w   = (const float*)d_in[8];
    const float* wa_b   = (const float*)d_in[9];
    float* out = (float*)d_out;

    // ws layout (float units) — proven 14,682,112-byte footprint:
    //   E1[262144] | E2[262144] | E3[512] | at_bf (2097152 f) | xt (1048576 f)
    // WhT/WlT alias the front of at_bf (live range prep1s->prep2x only).
    float* ws = (float*)d_ws;
    float* E1 = ws;
    float* E2 = ws + 262144;
    float* E3 = ws + 524288;
    unsigned short* at_bf = (unsigned short*)(ws + 524800);
    unsigned short* xt    = (unsigned short*)(ws + 524800 + 2097152);
    unsigned short* WhT   = at_bf;            // 65536 shorts
    unsigned short* WlT   = at_bf + 65536;    // 65536 shorts

    hipLaunchKernelGGL(prep1s_kernel, dim3(17), dim3(256), 0, stream,
                       ec, W1, W2, W3, b3, WhT, WlT, E3);
    hipLaunchKernelGGL(prep2x_kernel, dim3(768), dim3(256), 0, stream,
                       inputs, WhT, WlT, b1, b2, E1, E2, xt);
    hipLaunchKernelGGL(scores_kernel, dim3(512), dim3(256), 0, stream,
                       E1, E2, E3, wa_w, wa_b, at_bf);
    hipLaunchKernelGGL(av_mfma_kernel, dim3(DD / 64, TT / 64, BB), dim3(256), 0, stream,
                       at_bf, xt, out);
}